// Round 1
// baseline (89.951 us; speedup 1.0000x reference)
//
#include <hip/hip_runtime.h>

// Segment-mean + ReLU pooling.
// inputs: [num_nodes, 512] f32; idx: [num_graphs] i32 (contiguous segment
// starts, strictly increasing, idx[0]=0); out: [num_graphs, 512] f32.
//
// One block per segment. 512 threads = 128 float4-columns x 4 row-groups.
// Each thread streams its float4 column across its row-group (stride 4),
// LDS-reduces the 4 partials, scales by 1/count, relu, float4 store.

#define D_FEAT 512
#define NCOL4 (D_FEAT / 4)   // 128 float4 columns

__global__ __launch_bounds__(512) void seg_mean_relu_kernel(
    const float4* __restrict__ in,   // [num_nodes, NCOL4]
    const int* __restrict__ idx,     // [num_graphs]
    float4* __restrict__ out,        // [num_graphs, NCOL4]
    int num_nodes, int num_graphs) {
  const int b = blockIdx.x;
  if (b >= num_graphs) return;

  const int start = idx[b];
  const int end = (b + 1 < num_graphs) ? idx[b + 1] : num_nodes;

  const int col = threadIdx.x & (NCOL4 - 1);  // 0..127
  const int grp = threadIdx.x >> 7;           // 0..3

  float4 acc = make_float4(0.f, 0.f, 0.f, 0.f);
  // 64-bit safe base: row * NCOL4 can reach ~25.6M, fits int, but be explicit.
  for (int r = start + grp; r < end; r += 4) {
    float4 v = in[(size_t)r * NCOL4 + col];
    acc.x += v.x;
    acc.y += v.y;
    acc.z += v.z;
    acc.w += v.w;
  }

  __shared__ float4 part[3][NCOL4];
  if (grp > 0) part[grp - 1][col] = acc;
  __syncthreads();

  if (grp == 0) {
#pragma unroll
    for (int g = 0; g < 3; ++g) {
      float4 p = part[g][col];
      acc.x += p.x;
      acc.y += p.y;
      acc.z += p.z;
      acc.w += p.w;
    }
    const int cnt = end - start;
    const float s = (cnt > 0) ? (1.0f / (float)cnt) : 0.0f;
    float4 o;
    o.x = fmaxf(acc.x * s, 0.0f);
    o.y = fmaxf(acc.y * s, 0.0f);
    o.z = fmaxf(acc.z * s, 0.0f);
    o.w = fmaxf(acc.w * s, 0.0f);
    out[(size_t)b * NCOL4 + col] = o;
  }
}

extern "C" void kernel_launch(void* const* d_in, const int* in_sizes, int n_in,
                              void* d_out, int out_size, void* d_ws, size_t ws_size,
                              hipStream_t stream) {
  const float4* in = (const float4*)d_in[0];
  const int* idx = (const int*)d_in[1];
  float4* out = (float4*)d_out;

  const int num_nodes = in_sizes[0] / D_FEAT;  // 200000
  const int num_graphs = in_sizes[1];          // 1024

  seg_mean_relu_kernel<<<dim3(num_graphs), dim3(512), 0, stream>>>(
      in, idx, out, num_nodes, num_graphs);
}

// Round 2
// 88.817 us; speedup vs baseline: 1.0128x; 1.0128x over previous
//
#include <hip/hip_runtime.h>

// Segment-mean + ReLU pooling, load-balanced version.
// inputs: [num_nodes, 512] f32; idx: [num_graphs] i32 (contiguous segment
// starts, strictly increasing, idx[0]=0); out: [num_graphs, 512] f32.
//
// R0 lesson: one-block-per-segment is straggler-bound (segment sizes vary
// 0..2x mean; all blocks co-resident -> kernel time = max per-CU work,
// ~1.5x mean). Fix: blocks own FIXED 196-row chunks (1024 chunks = 4/CU,
// perfectly balanced); partial sums go to d_out via atomicAdd; separate
// zero + finalize kernels.

#define D_FEAT 512
#define NCOL4 (D_FEAT / 4)  // 128 float4 columns

__global__ __launch_bounds__(256) void zero_out_kernel(float4* __restrict__ out,
                                                       int n4) {
  int i = blockIdx.x * blockDim.x + threadIdx.x;
  if (i < n4) out[i] = make_float4(0.f, 0.f, 0.f, 0.f);
}

__global__ __launch_bounds__(512) void seg_accum_kernel(
    const float4* __restrict__ in,  // [num_nodes, NCOL4]
    const int* __restrict__ idx,    // [num_graphs]
    float* __restrict__ out,        // [num_graphs, D_FEAT], pre-zeroed
    int num_nodes, int num_graphs, int rows_per_blk) {
  const int r0 = blockIdx.x * rows_per_blk;
  if (r0 >= num_nodes) return;
  const int r1 = min(r0 + rows_per_blk, num_nodes);

  const int col = threadIdx.x & (NCOL4 - 1);  // 0..127
  const int grp = threadIdx.x >> 7;           // 0..3

  // largest s with idx[s] <= r0 (idx[0]==0 so s >= 0). Uniform across block;
  // idx is 4KB and L2-hot (every block reads it).
  int lo = 0, hi = num_graphs - 1;
  while (lo < hi) {
    int mid = (lo + hi + 1) >> 1;
    if (idx[mid] <= r0) lo = mid;
    else hi = mid - 1;
  }
  int s = lo;
  int row = r0;

  __shared__ float4 part[3][NCOL4];

  while (row < r1) {
    const int seg_end = (s + 1 < num_graphs) ? idx[s + 1] : num_nodes;
    const int e = min(seg_end, r1);

    float4 acc = make_float4(0.f, 0.f, 0.f, 0.f);
    for (int r = row + grp; r < e; r += 4) {
      float4 v = in[(size_t)r * NCOL4 + col];
      acc.x += v.x;
      acc.y += v.y;
      acc.z += v.z;
      acc.w += v.w;
    }

    if (grp > 0) part[grp - 1][col] = acc;
    __syncthreads();
    if (grp == 0) {
#pragma unroll
      for (int g = 0; g < 3; ++g) {
        float4 p = part[g][col];
        acc.x += p.x;
        acc.y += p.y;
        acc.z += p.z;
        acc.w += p.w;
      }
      float* o = out + (size_t)s * D_FEAT + col * 4;
      atomicAdd(o + 0, acc.x);
      atomicAdd(o + 1, acc.y);
      atomicAdd(o + 2, acc.z);
      atomicAdd(o + 3, acc.w);
    }
    __syncthreads();  // before part[] is reused for the next sub-segment

    row = e;
    ++s;
  }
}

__global__ __launch_bounds__(256) void finalize_kernel(
    float* __restrict__ out, const int* __restrict__ idx, int num_nodes,
    int num_graphs) {
  int i = blockIdx.x * blockDim.x + threadIdx.x;  // float4 index
  int total4 = num_graphs * NCOL4;
  if (i >= total4) return;
  int g = i >> 7;  // 128 float4 per row
  int start = idx[g];
  int end = (g + 1 < num_graphs) ? idx[g + 1] : num_nodes;
  float sInv = 1.0f / (float)(end - start);
  float4* o4 = (float4*)out;
  float4 v = o4[i];
  v.x = fmaxf(v.x * sInv, 0.f);
  v.y = fmaxf(v.y * sInv, 0.f);
  v.z = fmaxf(v.z * sInv, 0.f);
  v.w = fmaxf(v.w * sInv, 0.f);
  o4[i] = v;
}

extern "C" void kernel_launch(void* const* d_in, const int* in_sizes, int n_in,
                              void* d_out, int out_size, void* d_ws,
                              size_t ws_size, hipStream_t stream) {
  const float4* in = (const float4*)d_in[0];
  const int* idx = (const int*)d_in[1];
  float* out = (float*)d_out;

  const int num_nodes = in_sizes[0] / D_FEAT;  // 200000
  const int num_graphs = in_sizes[1];          // 1024

  const int out4 = num_graphs * NCOL4;  // 128K float4
  zero_out_kernel<<<dim3((out4 + 255) / 256), dim3(256), 0, stream>>>(
      (float4*)out, out4);

  const int nblocks = 1024;  // 4 chunks per CU, balanced
  const int rows_per_blk = (num_nodes + nblocks - 1) / nblocks;  // 196
  seg_accum_kernel<<<dim3(nblocks), dim3(512), 0, stream>>>(
      in, idx, out, num_nodes, num_graphs, rows_per_blk);

  finalize_kernel<<<dim3((out4 + 255) / 256), dim3(256), 0, stream>>>(
      out, idx, num_nodes, num_graphs);
}

// Round 3
// 88.794 us; speedup vs baseline: 1.0130x; 1.0003x over previous
//
#include <hip/hip_runtime.h>

// Segment-mean + ReLU pooling, R2: sequential-stream reads.
// inputs: [num_nodes, 512] f32; idx: [num_graphs] i32; out: [num_graphs,512] f32.
//
// R0/R1 lesson: both strided-row layouts capped at ~4.7 TB/s read BW while
// fill kernels hit 6.8 TB/s. Theory: per-thread 8KB row stride wrecks DRAM
// page locality and 1 outstanding load/wave limits MLP. Fix: each wave
// streams a CONTIGUOUS eighth of the sub-segment's rows flat (1KB requests,
// back-to-back), dual accumulators handle the lane->column parity, 4x
// unrolled independent loads. Balanced 196-row chunks + atomics kept from R1.

#define D_FEAT 512
#define NCOL4 (D_FEAT / 4)  // 128 float4 columns

__global__ __launch_bounds__(256) void zero_out_kernel(float4* __restrict__ out,
                                                       int n4) {
  int i = blockIdx.x * blockDim.x + threadIdx.x;
  if (i < n4) out[i] = make_float4(0.f, 0.f, 0.f, 0.f);
}

__global__ __launch_bounds__(512) void seg_accum_kernel(
    const float4* __restrict__ in,  // [num_nodes, NCOL4]
    const int* __restrict__ idx,    // [num_graphs]
    float* __restrict__ out,        // [num_graphs, D_FEAT], pre-zeroed
    int num_nodes, int num_graphs, int rows_per_blk) {
  const int r0 = blockIdx.x * rows_per_blk;
  if (r0 >= num_nodes) return;
  const int r1 = min(r0 + rows_per_blk, num_nodes);

  const int lane = threadIdx.x & 63;
  const int w = threadIdx.x >> 6;     // wave id 0..7
  const int col = threadIdx.x & 127;  // float4 column (reduction phase)
  const int g = threadIdx.x >> 7;

  __shared__ float4 part[8][NCOL4];  // 16 KB

  // largest s with idx[s] <= r0 (block-uniform; idx is 4KB, L2-hot)
  int lo = 0, hi = num_graphs - 1;
  while (lo < hi) {
    int mid = (lo + hi + 1) >> 1;
    if (idx[mid] <= r0) lo = mid;
    else hi = mid - 1;
  }
  int s = lo;
  int row = r0;

  while (row < r1) {
    const int seg_end = (s + 1 < num_graphs) ? idx[s + 1] : num_nodes;
    const int e = min(seg_end, r1);
    const int n = e - row;

    // wave w streams contiguous rows [ws, we) of this sub-segment, flat.
    const int ws = row + (n * w) / 8;
    const int we = row + (n * (w + 1)) / 8;

    float4 accA = make_float4(0.f, 0.f, 0.f, 0.f);  // column `lane`
    float4 accB = make_float4(0.f, 0.f, 0.f, 0.f);  // column `lane+64`

    int j = ws * NCOL4 + lane;
    const int jend = we * NCOL4;
    // main loop: 4 independent loads in flight per wave
    for (; j + 192 < jend; j += 256) {
      float4 v0 = in[j];
      float4 v1 = in[j + 64];
      float4 v2 = in[j + 128];
      float4 v3 = in[j + 192];
      accA.x += v0.x; accA.y += v0.y; accA.z += v0.z; accA.w += v0.w;
      accB.x += v1.x; accB.y += v1.y; accB.z += v1.z; accB.w += v1.w;
      accA.x += v2.x; accA.y += v2.y; accA.z += v2.z; accA.w += v2.w;
      accB.x += v3.x; accB.y += v3.y; accB.z += v3.z; accB.w += v3.w;
    }
    // tail: parity of (j - lane)/64 selects accumulator (even -> col lane)
    for (; j < jend; j += 64) {
      float4 v = in[j];
      if ((((j - lane) >> 6) & 1) == 0) {
        accA.x += v.x; accA.y += v.y; accA.z += v.z; accA.w += v.w;
      } else {
        accB.x += v.x; accB.y += v.y; accB.z += v.z; accB.w += v.w;
      }
    }

    part[w][lane] = accA;
    part[w][lane + 64] = accB;
    __syncthreads();

    if (g == 0) {  // threads 0..127, one per float4 column
      float4 a = part[0][col];
#pragma unroll
      for (int ww = 1; ww < 8; ++ww) {
        float4 p = part[ww][col];
        a.x += p.x; a.y += p.y; a.z += p.z; a.w += p.w;
      }
      float* o = out + (size_t)s * D_FEAT + col * 4;
      atomicAdd(o + 0, a.x);
      atomicAdd(o + 1, a.y);
      atomicAdd(o + 2, a.z);
      atomicAdd(o + 3, a.w);
    }
    __syncthreads();  // part[] reused next sub-segment

    row = e;
    ++s;
  }
}

__global__ __launch_bounds__(256) void finalize_kernel(
    float* __restrict__ out, const int* __restrict__ idx, int num_nodes,
    int num_graphs) {
  int i = blockIdx.x * blockDim.x + threadIdx.x;  // float4 index
  int total4 = num_graphs * NCOL4;
  if (i >= total4) return;
  int gph = i >> 7;
  int start = idx[gph];
  int end = (gph + 1 < num_graphs) ? idx[gph + 1] : num_nodes;
  int cnt = end - start;
  float sInv = (cnt > 0) ? 1.0f / (float)cnt : 0.0f;
  float4* o4 = (float4*)out;
  float4 v = o4[i];
  v.x = fmaxf(v.x * sInv, 0.f);
  v.y = fmaxf(v.y * sInv, 0.f);
  v.z = fmaxf(v.z * sInv, 0.f);
  v.w = fmaxf(v.w * sInv, 0.f);
  o4[i] = v;
}

extern "C" void kernel_launch(void* const* d_in, const int* in_sizes, int n_in,
                              void* d_out, int out_size, void* d_ws,
                              size_t ws_size, hipStream_t stream) {
  const float4* in = (const float4*)d_in[0];
  const int* idx = (const int*)d_in[1];
  float* out = (float*)d_out;

  const int num_nodes = in_sizes[0] / D_FEAT;  // 200000
  const int num_graphs = in_sizes[1];          // 1024

  const int out4 = num_graphs * NCOL4;
  zero_out_kernel<<<dim3((out4 + 255) / 256), dim3(256), 0, stream>>>(
      (float4*)out, out4);

  const int nblocks = 1024;  // 4 equal chunks per CU
  const int rows_per_blk = (num_nodes + nblocks - 1) / nblocks;  // 196
  seg_accum_kernel<<<dim3(nblocks), dim3(512), 0, stream>>>(
      in, idx, out, num_nodes, num_graphs, rows_per_blk);

  finalize_kernel<<<dim3((out4 + 255) / 256), dim3(256), 0, stream>>>(
      out, idx, num_nodes, num_graphs);
}